// Round 5
// baseline (701.175 us; speedup 1.0000x reference)
//
#include <hip/hip_runtime.h>
#include <hip/hip_bf16.h>
#include <math.h>

#define BN 4
#define CHN 64
#define HH 256
#define WW 256
#define HWSZ (HH*WW)
#define EPSV 1e-5f
#define CP 72   // LDS px-row stride in shorts (144 B): 16B-aligned, no bank conflicts (r4-measured 0)

typedef __attribute__((ext_vector_type(8)))  short  short8;
typedef __attribute__((ext_vector_type(4)))  short  short4v;
typedef __attribute__((ext_vector_type(16))) float  floatx16;

__device__ __forceinline__ int refl(int i, int n){ if(i<0)i=-i; if(i>=n)i=2*n-2-i; return i; }
__device__ __forceinline__ short f2bf(float f){ __hip_bfloat16 h=__float2bfloat16(f); return __builtin_bit_cast(short,h); }
__device__ __forceinline__ float bf2f(short s){ unsigned u=((unsigned)(unsigned short)s)<<16; return __builtin_bit_cast(float,u); }

// ---------------- guide: K[b,t,y,x] = exp(-0.5*(g_shift - g)^2), fp32 ----------------
__global__ void guide_kernel(const float* __restrict__ x, float* __restrict__ Kb) {
    int idx = blockIdx.x * 256 + threadIdx.x;
    if (idx >= BN*HWSZ) return;
    int b = idx / HWSZ, p = idx - b*HWSZ;
    int y = p / WW, xx = p - y*WW;
    const float* g = x + b*HWSZ;
    float gc = g[p];
#pragma unroll
    for (int t = 0; t < 9; ++t) {
        int yy  = refl(y + t/3 - 1, HH);
        int xx2 = refl(xx + t%3 - 1, WW);
        float d = g[yy*WW + xx2] - gc;
        Kb[(b*9 + t)*HWSZ + p] = __expf(-0.5f*d*d);
    }
}

// ---------------- pack all 7 weight tensors into 32x32x16 A-fragment order ----------------
// frag = (t*4+cg)*2+oh ; o = oh*32+(lane&31) ; c = cg*16+(lane>>5)*8+j
__global__ void pack_all(const float* w1,const float* w2,const float* w3,const float* w4,
                         const float* w5,const float* w6,const float* w7, short* __restrict__ Ap){
    const float* wsrc[7] = {w1,w2,w3,w4,w5,w6,w7};
    int layer = blockIdx.y;
    int tid = blockIdx.x*256 + threadIdx.x;          // 0..36863
    int j    = tid & 7;
    int lane = (tid >> 3) & 63;
    int frag = tid >> 9;                             // 0..71
    int oh = frag & 1, cg = (frag >> 1) & 3, t = frag >> 3;
    int o = oh*32 + (lane & 31);
    int c = cg*16 + (lane >> 5)*8 + j;
    Ap[(size_t)layer*36864 + tid] = f2bf(wsrc[layer][(o*CHN + c)*9 + t]);
}

// ---------------- conv1x1 -> A, channels-last bf16 [b][y][x][c] ----------------
__global__ void conv1x1_kernel(const float* __restrict__ x, const float* __restrict__ w0,
                               const float* __restrict__ b0, short* __restrict__ A){
    int idx = blockIdx.x*256 + threadIdx.x;          // BN*HWSZ*8 (px-octets)
    int oc = idx & 7;
    int px = (idx >> 3) % HWSZ;
    int b  = idx / (HWSZ*8);
    float xv = x[(size_t)b*HWSZ + px];
    short8 r;
#pragma unroll
    for (int j = 0; j < 8; ++j) {
        int c = oc*8 + j;
        r[j] = f2bf(fmaf(w0[c], xv, b0[c]));
    }
    *(short8*)(A + ((size_t)(b*HWSZ + px))*64 + oc*8) = r;
}

// ---------------- zero the stats accumulators (6 layers x [4][64][2]) ----------------
__global__ void zero_stats(float* st){
    int idx = blockIdx.x*256 + threadIdx.x;
    if (idx < 6*BN*64*2) st[idx] = 0.f;
}

// ---------------- PAC conv, implicit GEMM on mfma_32x32x16_bf16 ----------------
// Block: 64 o x (32 px x 4 rows). Wave w = output row y0+w, BOTH o-halves:
// each B-frag (ds_read_b128) feeds TWO mfma (af0/af1) -> 4x fewer LDS reads than r4.
// h halo (6 rows x 34 px x 64 c, bf16 channels-last) staged ONCE; taps read shifted
// windows. K applied per tap on the C-tile (col=lane&31 = pixel): acc += K[t,px]*(W_t x h).
// NORM=1: staging applies (v-mean)*rstd,relu from sum/sumsq stats (fuses applyrelu).
template<int NORM, int HASK, int FINAL>
__global__ void __launch_bounds__(256, 3) pac_mfma(
    const short* __restrict__ hin, const float* __restrict__ Kb,
    const short* __restrict__ Ap, const float* __restrict__ bias,
    const float* __restrict__ stin, short* __restrict__ outb, float* __restrict__ outf)
{
    __shared__ short lds[6*34*CP];                   // 29376 B

    int b  = blockIdx.z;
    int y0 = blockIdx.y * 4;
    int x0 = blockIdx.x * 32;
    int tid = threadIdx.x, lane = tid & 63, wave = tid >> 6;   // wave = wrow 0..3
    int ln2 = lane & 31, hi = lane >> 5;
    const short* hb = hin + (size_t)b*HWSZ*64;
    const float* stb = stin + b*64*2;

    // ---- stage 6 rows x 34 px x 64 c (16B chunks, coalesced; x uses refl for halo) ----
    float mean[8], rstd[8];
    if (NORM) {
        int c0 = (tid & 7) * 8;                      // thread's c-octet fixed (256%8==0)
#pragma unroll
        for (int j = 0; j < 8; ++j) {
            float s = stb[(c0+j)*2], s2 = stb[(c0+j)*2+1];
            float m = s * (1.f/HWSZ);
            float var = s2 * (1.f/HWSZ) - m*m;
            mean[j] = m; rstd[j] = rsqrtf(fmaxf(var, 0.f) + EPSV);
        }
    }
#pragma unroll
    for (int it = 0; it < 7; ++it) {
        int chunk = it*256 + tid;                    // 6*34*8 = 1632 chunks
        if (chunk < 1632) {
            int r = chunk / 272;
            int rem = chunk - r*272;
            int px = rem >> 3, oc = rem & 7;
            int yy = refl(y0 - 1 + r, HH);
            int xx = refl(x0 + px - 1, WW);
            short8 v = *(const short8*)(hb + ((size_t)(yy*WW + xx))*64 + oc*8);
            if (NORM) {
#pragma unroll
                for (int j = 0; j < 8; ++j) {
                    float f = bf2f(v[j]);
                    f = fmaxf((f - mean[j]) * rstd[j], 0.f);
                    v[j] = f2bf(f);
                }
            }
            *(short8*)(lds + (r*34 + px)*CP + oc*8) = v;
        }
    }
    __syncthreads();

    // ---- per-lane K values (pixel x0+ln2, row y0+wave) ----
    float kv[9];
    if (HASK) {
#pragma unroll
        for (int t = 0; t < 9; ++t)
            kv[t] = Kb[((size_t)(b*9 + t))*HWSZ + (y0 + wave)*WW + x0 + ln2];
    }

    floatx16 acc[2] = {(floatx16)(0.f), (floatx16)(0.f)};
    const short8* Ap8 = (const short8*)Ap;
#pragma unroll
    for (int t = 0; t < 9; ++t) {
        int dy = t/3 - 1, dx = t%3 - 1;
        int rr = wave + dy + 1;                      // 0..5
        floatx16 t0 = (floatx16)(0.f), t1 = (floatx16)(0.f);
#pragma unroll
        for (int cg = 0; cg < 4; ++cg) {
            short8 bf  = *(const short8*)(lds + (rr*34 + 1 + ln2 + dx)*CP + cg*16 + hi*8);
            short8 af0 = Ap8[((size_t)(t*4 + cg)*2 + 0)*64 + lane];
            short8 af1 = Ap8[((size_t)(t*4 + cg)*2 + 1)*64 + lane];
            if (HASK) {
                t0 = __builtin_amdgcn_mfma_f32_32x32x16_bf16(af0, bf, t0, 0, 0, 0);
                t1 = __builtin_amdgcn_mfma_f32_32x32x16_bf16(af1, bf, t1, 0, 0, 0);
            } else {
                acc[0] = __builtin_amdgcn_mfma_f32_32x32x16_bf16(af0, bf, acc[0], 0, 0, 0);
                acc[1] = __builtin_amdgcn_mfma_f32_32x32x16_bf16(af1, bf, acc[1], 0, 0, 0);
            }
        }
        if (HASK) {
#pragma unroll
            for (int r = 0; r < 16; ++r) {
                acc[0][r] = fmaf(kv[t], t0[r], acc[0][r]);
                acc[1][r] = fmaf(kv[t], t1[r], acc[1][r]);
            }
        }
    }

    // ---- epilogue: C/D col=lane&31 (px), row o = (reg&3)+8*(reg>>2)+4*hi (+32*oh) ----
    int y = y0 + wave, x = x0 + ln2;
#pragma unroll
    for (int oh = 0; oh < 2; ++oh) {
#pragma unroll
        for (int q = 0; q < 4; ++q) {
            int o0 = oh*32 + hi*4 + 8*q;             // regs 4q..4q+3 -> o0..o0+3
            float4 bq = *(const float4*)(bias + o0);
            if (FINAL) {
#pragma unroll
                for (int jj = 0; jj < 4; ++jj) {
                    float val = acc[oh][q*4 + jj] + ((float*)&bq)[jj];
                    val = fmaxf(val, 0.f);
                    outf[((size_t)(b*64 + o0 + jj))*HWSZ + y*WW + x] = val;  // NCHW fp32
                }
            } else {
                short4v pk;
#pragma unroll
                for (int jj = 0; jj < 4; ++jj) pk[jj] = f2bf(acc[oh][q*4 + jj] + ((float*)&bq)[jj]);
                *(short4v*)(outb + ((size_t)b*HWSZ + (size_t)(y*WW + x))*64 + o0) = pk;
            }
        }
    }
}

// ---------------- stats: per-(b,c) sum/sumsq of bf16 channels-last tensor ----------------
__global__ void __launch_bounds__(256) stats_k(const short* __restrict__ t, float* __restrict__ st){
    int b = blockIdx.y, chunk = blockIdx.x;          // 64 chunks of 1024 px
    int tid = threadIdx.x, oc = tid & 7, pxl = tid >> 3;
    const short* tb = t + (size_t)b*HWSZ*64;
    float s[8] = {0}, s2[8] = {0};
    for (int i = 0; i < 32; ++i) {
        int px = chunk*1024 + i*32 + pxl;
        short8 v = *(const short8*)(tb + (size_t)px*64 + oc*8);
#pragma unroll
        for (int j = 0; j < 8; ++j) { float f = bf2f(v[j]); s[j] += f; s2[j] += f*f; }
    }
#pragma unroll
    for (int mask = 8; mask <= 32; mask <<= 1) {
#pragma unroll
        for (int j = 0; j < 8; ++j) { s[j] += __shfl_xor(s[j], mask); s2[j] += __shfl_xor(s2[j], mask); }
    }
    __shared__ float sm[4][8][16];
    int lane = tid & 63, wave = tid >> 6;
    if (lane < 8) {
#pragma unroll
        for (int j = 0; j < 8; ++j) { sm[wave][lane][j] = s[j]; sm[wave][lane][8+j] = s2[j]; }
    }
    __syncthreads();
    if (tid < 8) {
#pragma unroll
        for (int j = 0; j < 8; ++j) {
            float a = 0, bsq = 0;
#pragma unroll
            for (int w = 0; w < 4; ++w) { a += sm[w][tid][j]; bsq += sm[w][tid][8+j]; }
            atomicAdd(&st[(b*64 + tid*8 + j)*2],     a);
            atomicAdd(&st[(b*64 + tid*8 + j)*2 + 1], bsq);
        }
    }
}

// ---------------- A <- relu(A + (C-mean)*rstd), bf16 channels-last ----------------
__global__ void addnorm_relu(short* __restrict__ A, const short* __restrict__ C,
                             const float* __restrict__ st){
    int idx = blockIdx.x*256 + threadIdx.x;          // BN*HWSZ*8
    int oc = idx & 7;
    size_t pq = (size_t)(idx >> 3);
    int b = (int)(pq / HWSZ);
    size_t base = pq*64 + oc*8;
    short8 a = *(short8*)(A + base);
    short8 c = *(const short8*)(C + base);
#pragma unroll
    for (int j = 0; j < 8; ++j) {
        int cc = oc*8 + j;
        float s = st[(b*64+cc)*2], s2 = st[(b*64+cc)*2+1];
        float m = s * (1.f/HWSZ);
        float rs = rsqrtf(fmaxf(s2*(1.f/HWSZ) - m*m, 0.f) + EPSV);
        float f = bf2f(a[j]) + (bf2f(c[j]) - m)*rs;
        a[j] = f2bf(fmaxf(f, 0.f));
    }
    *(short8*)(A + base) = a;
}

extern "C" void kernel_launch(void* const* d_in, const int* in_sizes, int n_in,
                              void* d_out, int out_size, void* d_ws, size_t ws_size,
                              hipStream_t stream) {
    const float* x   = (const float*)d_in[0];
    // d_in[1] = grad_img: unused by the reference
    const float* w0  = (const float*)d_in[2];
    const float* b0  = (const float*)d_in[3];
    const float* wf  = (const float*)d_in[4];
    const float* bf  = (const float*)d_in[5];
    const float* w1a = (const float*)d_in[6];  const float* b1a = (const float*)d_in[7];
    const float* w1b = (const float*)d_in[8];  const float* b1b = (const float*)d_in[9];
    const float* w2a = (const float*)d_in[10]; const float* b2a = (const float*)d_in[11];
    const float* w2b = (const float*)d_in[12]; const float* b2b = (const float*)d_in[13];
    const float* w3a = (const float*)d_in[14]; const float* b3a = (const float*)d_in[15];
    const float* w3b = (const float*)d_in[16]; const float* b3b = (const float*)d_in[17];

    float* ws   = (float*)d_ws;
    float* Kb   = ws;                                 // 2,359,296 f (9.4 MB)
    short* A    = (short*)(Kb + (size_t)BN*9*HWSZ);   // 16,777,216 shorts (33.5 MB)
    short* Bb   = A + (size_t)BN*HWSZ*64;             // 16,777,216 shorts
    short* Apk  = Bb + (size_t)BN*HWSZ*64;            // 7*36864 shorts
    float* st   = (float*)(Apk + (size_t)7*36864 + 64); // 6 * 512 floats
    short* Cc   = (short*)d_out;                      // C scratch (bf16), then fp32 output

    zero_stats<<<12, 256, 0, stream>>>(st);
    pack_all<<<dim3(144, 7), 256, 0, stream>>>(w1a, w1b, w2a, w2b, w3a, w3b, wf, Apk);
    guide_kernel<<<(BN*HWSZ + 255)/256, 256, 0, stream>>>(x, Kb);
    conv1x1_kernel<<<BN*HWSZ*8/256, 256, 0, stream>>>(x, w0, b0, A);

    dim3 g(WW/32, HH/4, BN);                          // 8 x 64 x 4 = 2048 blocks
    const int eblk = BN*HWSZ*8/256;
    const float* biasA[3] = {b1a, b2a, b3a};
    const float* biasB[3] = {b1b, b2b, b3b};

    for (int rb = 0; rb < 3; ++rb) {
        float* stB = st + (size_t)(2*rb)   * BN*64*2;
        float* stC = st + (size_t)(2*rb+1) * BN*64*2;
        // pac_a: raw staging, K-modulated, bf16 out
        pac_mfma<0,1,0><<<g, 256, 0, stream>>>(A, Kb, Apk + (size_t)(2*rb)*36864, biasA[rb],
                                               nullptr, Bb, nullptr);
        stats_k<<<dim3(64, BN), 256, 0, stream>>>(Bb, stB);
        // pac_b: staging applies norm(B)+relu, K-modulated, bf16 out
        pac_mfma<1,1,0><<<g, 256, 0, stream>>>(Bb, Kb, Apk + (size_t)(2*rb+1)*36864, biasB[rb],
                                               stB, Cc, nullptr);
        stats_k<<<dim3(64, BN), 256, 0, stream>>>(Cc, stC);
        addnorm_relu<<<eblk, 256, 0, stream>>>(A, Cc, stC);
    }

    // final: plain 3x3 conv (no K), bias+relu, fp32 NCHW to d_out
    pac_mfma<0,0,1><<<g, 256, 0, stream>>>(A, Kb, Apk + (size_t)6*36864, bf,
                                           nullptr, nullptr, (float*)d_out);
}